// Round 1
// baseline (661.947 us; speedup 1.0000x reference)
//
#include <hip/hip_runtime.h>

typedef __attribute__((ext_vector_type(8))) __bf16 bf16x8;
typedef __attribute__((ext_vector_type(4))) float f32x4;

// ---------- fp32 -> bf16 (round-to-nearest-even) ----------
__device__ __forceinline__ unsigned short f2b(float f) {
    union { float f; unsigned u; } v; v.f = f;
    unsigned u = v.u;
    return (unsigned short)((u + 0x7fffu + ((u >> 16) & 1u)) >> 16);
}

__global__ void cvt_f32_bf16(const float* __restrict__ in,
                             unsigned short* __restrict__ out, long n) {
    long i = ((long)blockIdx.x * blockDim.x + threadIdx.x) * 4;
    long stride = (long)gridDim.x * blockDim.x * 4;
    for (; i < n; i += stride) {
        float4 v = *(const float4*)(in + i);
        ushort4 o;
        o.x = f2b(v.x); o.y = f2b(v.y); o.z = f2b(v.z); o.w = f2b(v.w);
        *(ushort4*)(out + i) = o;
    }
}

// ---------- scatter 32 trainable 256x256 blocks into bf16 weight ----------
__global__ void scatter_blocks(const float* __restrict__ sel,
                               const int* __restrict__ idx,
                               unsigned short* __restrict__ Wb) {
    int b = blockIdx.x;  // 0..31
    // Detect int64-vs-int32 index storage: if int64, every odd int32 is a hi
    // word == 0. With 32 random (row,col) pairs, all-cols-zero is impossible.
    bool is64 = true;
    for (int j = 1; j < 64; j += 2) {
        if (idx[j] != 0) { is64 = false; break; }
    }
    int ro, co;
    if (is64) { ro = idx[4 * b]; co = idx[4 * b + 2]; }
    else      { ro = idx[2 * b]; co = idx[2 * b + 1]; }
    const float* src = sel + (size_t)b * 256 * 256;
    unsigned short* dst = Wb + (size_t)(ro * 256) * 4096 + (size_t)co * 256;
    int t = threadIdx.x;  // 256 threads, one column each
    for (int r = 0; r < 256; ++r) {
        dst[(size_t)r * 4096 + t] = f2b(src[r * 256 + t]);
    }
}

// ---------- async global -> LDS, 16 B per lane ----------
__device__ __forceinline__ void gload_lds16(const unsigned short* g,
                                            unsigned short* l) {
    __builtin_amdgcn_global_load_lds(
        (__attribute__((address_space(1))) void*)(g),
        (__attribute__((address_space(3))) void*)(l), 16, 0, 0);
}

// ---------- bf16 GEMM: C[M][N] = A[M][K] * B[N][K]^T  (m97 structure) ----------
// 128x128 tile, BK=32, 256 threads (4 waves, 2x2), 4x4 16x16x32 MFMA frags/wave
__global__ __launch_bounds__(256) void gemm_bt(
    const unsigned short* __restrict__ A,  // [M][K] bf16
    const unsigned short* __restrict__ B,  // [N][K] bf16
    float* __restrict__ C,                 // [M][N] fp32
    int M, int N, int K) {
    __shared__ unsigned short As[128 * 32];  // 8 KiB
    __shared__ unsigned short Bs[128 * 32];  // 8 KiB

    const int tid  = threadIdx.x;
    const int lane = tid & 63;
    const int wid  = tid >> 6;
    const int wm   = wid >> 1;   // 2 waves along M
    const int wn   = wid & 1;    // 2 waves along N

    // --- XCD-aware bijective swizzle (nwg = 2048, divisible by 8) ---
    const int nwg = gridDim.x;
    const int cpx = nwg >> 3;
    const int wg  = blockIdx.x;
    const int swz = (wg & 7) * cpx + (wg >> 3);
    const int bn  = swz & 31;    // N / 128 = 32
    const int bm  = swz >> 5;    // M / 128 = 64

    // --- staging addresses: tile is [128 rows][32 k] bf16, linear in LDS ---
    // 512 chunks of 16 B; thread t handles chunks t and t+256.
    const int c0 = tid, c1 = tid + 256;
    const size_t aBase = (size_t)bm * 128 * K;
    const size_t bBase = (size_t)bn * 128 * K;
    const unsigned short* gA0 = A + aBase + (size_t)(c0 >> 2) * K + (c0 & 3) * 8;
    const unsigned short* gA1 = A + aBase + (size_t)(c1 >> 2) * K + (c1 & 3) * 8;
    const unsigned short* gB0 = B + bBase + (size_t)(c0 >> 2) * K + (c0 & 3) * 8;
    const unsigned short* gB1 = B + bBase + (size_t)(c1 >> 2) * K + (c1 & 3) * 8;
    // wave-uniform LDS dest base (HW adds lane*16 bytes)
    unsigned short* lA0 = As + (size_t)(tid & 192) * 8;
    unsigned short* lA1 = As + 2048 + (size_t)(tid & 192) * 8;
    unsigned short* lB0 = Bs + (size_t)(tid & 192) * 8;
    unsigned short* lB1 = Bs + 2048 + (size_t)(tid & 192) * 8;

    const int lrow = lane & 15;
    const int kb   = (lane >> 4) * 8;

    f32x4 acc[4][4] = {};

    for (int k0 = 0; k0 < K; k0 += 32) {
        __syncthreads();  // previous tile fully consumed
        gload_lds16(gA0 + k0, lA0);
        gload_lds16(gA1 + k0, lA1);
        gload_lds16(gB0 + k0, lB0);
        gload_lds16(gB1 + k0, lB1);
        __syncthreads();  // compiler drains vmcnt before barrier

        bf16x8 af[4], bf[4];
#pragma unroll
        for (int im = 0; im < 4; ++im)
            af[im] = *(const bf16x8*)(As + (wm * 64 + im * 16 + lrow) * 32 + kb);
#pragma unroll
        for (int in = 0; in < 4; ++in)
            bf[in] = *(const bf16x8*)(Bs + (wn * 64 + in * 16 + lrow) * 32 + kb);
#pragma unroll
        for (int im = 0; im < 4; ++im)
#pragma unroll
            for (int in = 0; in < 4; ++in)
                acc[im][in] = __builtin_amdgcn_mfma_f32_16x16x32_bf16(
                    af[im], bf[in], acc[im][in], 0, 0, 0);
    }

    // --- epilogue: C/D layout col = lane&15, row = (lane>>4)*4 + reg ---
    const int crow = (lane >> 4) * 4;
    const int ccol = lane & 15;
    const size_t cbase =
        (size_t)(bm * 128 + wm * 64) * N + (size_t)(bn * 128 + wn * 64);
#pragma unroll
    for (int im = 0; im < 4; ++im)
#pragma unroll
        for (int in = 0; in < 4; ++in)
#pragma unroll
            for (int r = 0; r < 4; ++r)
                C[cbase + (size_t)(im * 16 + crow + r) * N + in * 16 + ccol] =
                    acc[im][in][r];
}

extern "C" void kernel_launch(void* const* d_in, const int* in_sizes, int n_in,
                              void* d_out, int out_size, void* d_ws,
                              size_t ws_size, hipStream_t stream) {
    const float* x    = (const float*)d_in[0];  // [4,2048,4096]
    const float* selw = (const float*)d_in[1];  // [8192,256]
    const float* w    = (const float*)d_in[2];  // [4096,4096]
    const int*   idx  = (const int*)d_in[3];    // [32,2]
    float* out = (float*)d_out;                 // [4,2048,4096]

    const int M = 8192, N = 4096, K = 4096;

    unsigned short* Xb = (unsigned short*)d_ws;                       // 64 MiB
    unsigned short* Wb = (unsigned short*)((char*)d_ws + (size_t)64 * 1024 * 1024);  // 32 MiB

    cvt_f32_bf16<<<4096, 256, 0, stream>>>(x, Xb, (long)M * K);
    cvt_f32_bf16<<<2048, 256, 0, stream>>>(w, Wb, (long)N * K);
    scatter_blocks<<<32, 256, 0, stream>>>(selw, idx, Wb);

    gemm_bt<<<2048, 256, 0, stream>>>(Xb, Wb, out, M, N, K);
}

// Round 4
// 524.489 us; speedup vs baseline: 1.2621x; 1.2621x over previous
//
#include <hip/hip_runtime.h>

typedef __attribute__((ext_vector_type(8))) __bf16 bf16x8;
typedef __attribute__((ext_vector_type(4))) float f32x4;
typedef __attribute__((ext_vector_type(8))) unsigned short ushort8_t;
typedef unsigned short u16;

// ---------- fp32 -> bf16 (round-to-nearest-even) ----------
__device__ __forceinline__ u16 f2b(float f) {
    union { float f; unsigned u; } v; v.f = f;
    unsigned u = v.u;
    return (u16)((u + 0x7fffu + ((u >> 16) & 1u)) >> 16);
}

__global__ void cvt8(const float* __restrict__ in, u16* __restrict__ out, long n) {
    long i = ((long)blockIdx.x * blockDim.x + threadIdx.x) * 8;
    if (i >= n) return;
    float4 v0 = *(const float4*)(in + i);
    float4 v1 = *(const float4*)(in + i + 4);
    ushort8_t o;
    o[0] = f2b(v0.x); o[1] = f2b(v0.y); o[2] = f2b(v0.z); o[3] = f2b(v0.w);
    o[4] = f2b(v1.x); o[5] = f2b(v1.y); o[6] = f2b(v1.z); o[7] = f2b(v1.w);
    *(ushort8_t*)(out + i) = o;
}

// ---------- scatter 32 trainable 256x256 blocks (2048 blocks, parallel) ----------
__global__ void scatter2(const float* __restrict__ sel, const int* __restrict__ idx,
                         u16* __restrict__ Wb) {
    int blk = blockIdx.x >> 6;   // 0..31
    int s   = blockIdx.x & 63;   // 4-row chunk within the 256x256 block
    // int64 vs int32 index autodetect (hi words all zero => int64)
    bool is64 = true;
    for (int j = 1; j < 64; j += 2)
        if (idx[j] != 0) { is64 = false; break; }
    int ro, co;
    if (is64) { ro = idx[4 * blk]; co = idx[4 * blk + 2]; }
    else      { ro = idx[2 * blk]; co = idx[2 * blk + 1]; }
    int t = threadIdx.x;
    int r = s * 4 + (t >> 6);
    int c = (t & 63) * 4;
    float4 v = *(const float4*)(sel + ((size_t)blk * 256 + r) * 256 + c);
    ushort4 o;
    o.x = f2b(v.x); o.y = f2b(v.y); o.z = f2b(v.z); o.w = f2b(v.w);
    *(ushort4*)(Wb + (size_t)(ro * 256 + r) * 4096 + (size_t)co * 256 + c) = o;
}

// ---------- async global -> LDS, 16 B per lane ----------
__device__ __forceinline__ void gload_lds16(const u16* g, u16* l) {
    __builtin_amdgcn_global_load_lds(
        (__attribute__((address_space(1))) void*)(g),
        (__attribute__((address_space(3))) void*)(l), 16, 0, 0);
}

// ---------- swizzled LDS fragment read (T2: byte ^= (row&7)<<4) ----------
__device__ __forceinline__ bf16x8 ld_frag(const char* base, int R, int colB) {
    unsigned off = (unsigned)(R * 128 + colB) ^ ((unsigned)(R & 7) << 4);
    return *(const bf16x8*)(base + off);
}

#define BARRIER() __builtin_amdgcn_s_barrier()
#define LGKM0() asm volatile("s_waitcnt lgkmcnt(0)" ::: "memory")
#define VM6()   asm volatile("s_waitcnt vmcnt(6)" ::: "memory")
#define VM0()   asm volatile("s_waitcnt vmcnt(0)" ::: "memory")

// ====================== 256x256 8-phase bf16 GEMM ======================
// C[M][N] = A[M][K] * B[N][K]^T.  BM=BN=256, BK=64, 512 thr (8 waves 2Mx4N).
// LDS 128 KiB: As/Bs [2 dbuf][256*64].  Staging units are the per-quadrant
// consumption sets:
//   SA0 = A rows {0-63,128-191} (read in P1, mh=0), SA1 = {64-127,192-255} (P3)
//   SB0 = B rows {0-31,64-95,128-159,192-223} (P1, nh=0), SB1 = +32 (P2)
// Window(tile C, buf cur): P1 rd A0,B0, stage SA1(C+1)->other; P2 rd B1,
// stage SA0(C+2)->cur; P3 rd A1, stage SB0(C+2)->cur; P4 stage SB1(C+2)->cur,
// vmcnt(6).  Every stage targets a region whose last ds_read was in an
// earlier, barrier-separated phase.
__global__ __launch_bounds__(512, 2) void gemm256(
    const u16* __restrict__ A, const u16* __restrict__ B,
    float* __restrict__ C, int M, int N, int K) {
    __shared__ u16 As[2][16384];
    __shared__ u16 Bs[2][16384];

    const int tid  = threadIdx.x;
    const int lane = tid & 63;
    const int wid  = tid >> 6;
    const int wm   = wid >> 2;   // 0..1
    const int wn   = wid & 3;    // 0..3
    const int lrow  = lane & 15;
    const int kbyte = (lane >> 4) * 16;

    // T1: XCD swizzle (nwg = 512, divisible by 8)
    const int cpx = gridDim.x >> 3;
    const int swz = (blockIdx.x & 7) * cpx + (blockIdx.x >> 3);
    const int bn = swz & 15;   // N/256 = 16
    const int bm = swz >> 4;   // M/256 = 32

    // staging: chunk c = j*512 + tid, r = c>>3, colchunk = (c&7)^(r&7)
    const int r0  = tid >> 3;                 // 0..63
    const int r1  = (tid + 512) >> 3;         // 64..127
    const int cc0 = (tid & 7) ^ (r0 & 7);
    const int cc1 = (tid & 7) ^ (r1 & 7);
    const u16* gAj0 = A + (size_t)(bm * 256 + r0) * K + cc0 * 8;
    const u16* gAj1 = A + (size_t)(bm * 256 + 64 + r1) * K + cc1 * 8;
    const int bRow0 = ((r0 >> 5) * 64) + (r0 & 31);
    const int bRow1 = 128 + (((r1 - 64) >> 5) * 64) + ((r1 - 64) & 31);
    const u16* gBj0 = B + (size_t)(bn * 256 + bRow0) * K + cc0 * 8;
    const u16* gBj1 = B + (size_t)(bn * 256 + bRow1) * K + cc1 * 8;
    const int w8  = wid * 8;
    const int bb0 = ((w8 >> 5) << 12) + ((w8 & 31) << 6);  // B-unit LDS base

#define SA0(buf, T) { gload_lds16(gAj0 + (size_t)(T) * 64, &As[buf][wid * 512]); \
                      gload_lds16(gAj1 + (size_t)(T) * 64, &As[buf][8192 + wid * 512]); }
#define SA1(buf, T) { gload_lds16(gAj0 + (size_t)64 * K + (size_t)(T) * 64, &As[buf][4096 + wid * 512]); \
                      gload_lds16(gAj1 + (size_t)64 * K + (size_t)(T) * 64, &As[buf][12288 + wid * 512]); }
#define SB0(buf, T) { gload_lds16(gBj0 + (size_t)(T) * 64, &Bs[buf][bb0]); \
                      gload_lds16(gBj1 + (size_t)(T) * 64, &Bs[buf][8192 + bb0]); }
#define SB1(buf, T) { gload_lds16(gBj0 + (size_t)32 * K + (size_t)(T) * 64, &Bs[buf][2048 + bb0]); \
                      gload_lds16(gBj1 + (size_t)32 * K + (size_t)(T) * 64, &Bs[buf][10240 + bb0]); }

#define LDA(cur, mh, im, ks) ld_frag((const char*)&As[cur][0], wm * 128 + (mh) * 64 + (im) * 16 + lrow, (ks) * 64 + kbyte)
#define LDB(cur, nh, in2, ks) ld_frag((const char*)&Bs[cur][0], wn * 64 + (nh) * 32 + (in2) * 16 + lrow, (ks) * 64 + kbyte)

    f32x4 acc[8][4] = {};

#define MM(mh, nh, aa, bb) \
    _Pragma("unroll") for (int im = 0; im < 4; ++im) \
    _Pragma("unroll") for (int in2 = 0; in2 < 2; ++in2) { \
        acc[(mh)*4+im][(nh)*2+in2] = __builtin_amdgcn_mfma_f32_16x16x32_bf16(aa[im][0], bb[in2][0], acc[(mh)*4+im][(nh)*2+in2], 0, 0, 0); \
        acc[(mh)*4+im][(nh)*2+in2] = __builtin_amdgcn_mfma_f32_16x16x32_bf16(aa[im][1], bb[in2][1], acc[(mh)*4+im][(nh)*2+in2], 0, 0, 0); }

#define WINDOW(cur, S1, S2, S3, S4, VMST) { \
    bf16x8 aLo[4][2], aHi[4][2], bLo[2][2], bHi[2][2]; \
    /* P1: quadrant (0,0) */ \
    _Pragma("unroll") for (int im = 0; im < 4; ++im) { \
        aLo[im][0] = LDA(cur, 0, im, 0); aLo[im][1] = LDA(cur, 0, im, 1); } \
    _Pragma("unroll") for (int in2 = 0; in2 < 2; ++in2) { \
        bLo[in2][0] = LDB(cur, 0, in2, 0); bLo[in2][1] = LDB(cur, 0, in2, 1); } \
    S1; BARRIER(); LGKM0(); \
    __builtin_amdgcn_s_setprio(1); MM(0, 0, aLo, bLo); __builtin_amdgcn_s_setprio(0); BARRIER(); \
    /* P2: quadrant (0,1) */ \
    _Pragma("unroll") for (int in2 = 0; in2 < 2; ++in2) { \
        bHi[in2][0] = LDB(cur, 1, in2, 0); bHi[in2][1] = LDB(cur, 1, in2, 1); } \
    S2; BARRIER(); LGKM0(); \
    __builtin_amdgcn_s_setprio(1); MM(0, 1, aLo, bHi); __builtin_amdgcn_s_setprio(0); BARRIER(); \
    /* P3: quadrant (1,1) */ \
    _Pragma("unroll") for (int im = 0; im < 4; ++im) { \
        aHi[im][0] = LDA(cur, 1, im, 0); aHi[im][1] = LDA(cur, 1, im, 1); } \
    S3; BARRIER(); LGKM0(); \
    __builtin_amdgcn_s_setprio(1); MM(1, 1, aHi, bHi); __builtin_amdgcn_s_setprio(0); BARRIER(); \
    /* P4: quadrant (1,0) */ \
    S4; BARRIER(); LGKM0(); \
    __builtin_amdgcn_s_setprio(1); MM(1, 0, aHi, bLo); __builtin_amdgcn_s_setprio(0); \
    VMST; BARRIER(); \
}

    // prologue: tile0 fully + tile1 {SA0,SB0,SB1}; wait tile0 (8 oldest) landed
    SA0(0, 0); SB0(0, 0); SB1(0, 0); SA1(0, 0);
    SA0(1, 1); SB0(1, 1); SB1(1, 1);
    VM6(); BARRIER();

    for (int T = 0; T < 62; T += 2) {
        WINDOW(0, SA1(1, T + 1), SA0(0, T + 2), SB0(0, T + 2), SB1(0, T + 2), VM6());
        WINDOW(1, SA1(0, T + 2), SA0(1, T + 3), SB0(1, T + 3), SB1(1, T + 3), VM6());
    }
    // epilogue: windows 62, 63
    WINDOW(0, SA1(1, 63), (void)0, (void)0, (void)0, VM0());
    WINDOW(1, (void)0, (void)0, (void)0, (void)0, (void)0);

    // C write: row = A-frag row, col = B-frag row; C/D: col=lane&15, row=(lane>>4)*4+r
    const int crow = (lane >> 4) * 4;
    const int ccol = lane & 15;
    const size_t cb = (size_t)(bm * 256 + wm * 128) * N + bn * 256 + wn * 64;
#pragma unroll
    for (int mI = 0; mI < 8; ++mI)
#pragma unroll
        for (int nI = 0; nI < 4; ++nI)
#pragma unroll
            for (int r = 0; r < 4; ++r)
                C[cb + (size_t)(mI * 16 + crow + r) * N + nI * 16 + ccol] = acc[mI][nI][r];
}

extern "C" void kernel_launch(void* const* d_in, const int* in_sizes, int n_in,
                              void* d_out, int out_size, void* d_ws,
                              size_t ws_size, hipStream_t stream) {
    const float* x    = (const float*)d_in[0];  // [4,2048,4096]
    const float* selw = (const float*)d_in[1];  // [8192,256]
    const float* w    = (const float*)d_in[2];  // [4096,4096]
    const int*   idx  = (const int*)d_in[3];    // [32,2]
    float* out = (float*)d_out;                 // [4,2048,4096]

    const int M = 8192, N = 4096, K = 4096;

    u16* Xb = (u16*)d_ws;                                            // 64 MiB
    u16* Wb = (u16*)((char*)d_ws + (size_t)64 * 1024 * 1024);        // 32 MiB

    cvt8<<<16384, 256, 0, stream>>>(x, Xb, (long)M * K);
    cvt8<<<8192, 256, 0, stream>>>(w, Wb, (long)N * K);
    scatter2<<<2048, 256, 0, stream>>>(selw, idx, Wb);

    gemm256<<<512, 512, 0, stream>>>(Xb, Wb, out, M, N, K);
}